// Round 4
// baseline (10203.719 us; speedup 1.0000x reference)
//
#include <hip/hip_runtime.h>
#include <hip/hip_bf16.h>

// Problem constants
#define SEQ   4096
#define EMB   256
#define HHID  256      // HH
#define G4    1024     // 4*HH
#define NT    9        // tags
#define TSTART 7
#define TSTOP  8
#define NEGV  (-10000.0f)
#define POISON 0xAAAAAAAAu

// Workspace byte offsets (total ~42.2 MB)
#define WS_XG_F   0u            // 4096*1024 f32 = 16 MB
#define WS_XG_B   16777216u     // 16 MB
#define WS_HF     33554432u     // 4096*256 f32 = 4 MB
#define WS_HB     37748736u     // 4 MB
#define WS_FRAMES 41943040u     // 4096*9 f32 = 147456 B

// ---------------------------------------------------------------------------
// Kernel 1: x = embed[sentence]; xg = x @ w_ih^T + b_ih + b_hh  (both dirs)
// grid (256, 2), block 256. Each block: 16 sentence positions, all 1024 gates.
// ---------------------------------------------------------------------------
__global__ __launch_bounds__(256) void xgate_kernel(
    const int* __restrict__ sentence, const float* __restrict__ embed,
    const float* __restrict__ w_ih_f, const float* __restrict__ b_ih_f,
    const float* __restrict__ b_hh_f,
    const float* __restrict__ w_ih_b, const float* __restrict__ b_ih_b,
    const float* __restrict__ b_hh_b,
    float* __restrict__ xg_f, float* __restrict__ xg_b)
{
    const int st  = blockIdx.x;          // 0..255 (16 s each)
    const int dir = blockIdx.y;
    const float* w  = dir ? w_ih_b : w_ih_f;
    const float* bi = dir ? b_ih_b : b_ih_f;
    const float* bh = dir ? b_hh_b : b_hh_f;
    float* xg = dir ? xg_b : xg_f;
    const int t = threadIdx.x;

    __shared__ float x_t[EMB][16];       // transposed x tile
    for (int sl = 0; sl < 16; ++sl) {
        int s   = st * 16 + sl;
        int tok = sentence[s];
        x_t[t][sl] = embed[(size_t)tok * EMB + t];
    }
    __syncthreads();

    float acc[4][16];
    #pragma unroll
    for (int q = 0; q < 4; ++q)
        #pragma unroll
        for (int sl = 0; sl < 16; ++sl) acc[q][sl] = 0.f;

    #pragma unroll 4
    for (int e = 0; e < EMB; ++e) {
        float w0 = w[(size_t)(t        ) * EMB + e];
        float w1 = w[(size_t)(t + 256  ) * EMB + e];
        float w2 = w[(size_t)(t + 512  ) * EMB + e];
        float w3 = w[(size_t)(t + 768  ) * EMB + e];
        #pragma unroll
        for (int sl = 0; sl < 16; ++sl) {
            float xv = x_t[e][sl];
            acc[0][sl] += w0 * xv;
            acc[1][sl] += w1 * xv;
            acc[2][sl] += w2 * xv;
            acc[3][sl] += w3 * xv;
        }
    }

    #pragma unroll
    for (int q = 0; q < 4; ++q) {
        int g = t + 256 * q;
        float bb = bi[g] + bh[g];
        for (int sl = 0; sl < 16; ++sl) {
            xg[(size_t)(st * 16 + sl) * G4 + g] = acc[q][sl] + bb;
        }
    }
}

// ---------------------------------------------------------------------------
// Kernel 2: bidirectional LSTM recurrence. 16 blocks x 256 threads.
// blocks 0..7 = forward slices, 8..15 = backward slices.
// Each block owns 32 hidden units (128 gate rows); weights pinned in VGPRs
// via opaque inline asm (compiler cannot sink/remat the loads).
//
// Sync: data-carrying poison poll. hf/hb are pre-poisoned to 0xAAAAAAAA.
// Producers write h words with relaxed agent-scope atomic stores (no fence,
// no flag). Consumers (t<64, 4 words each, in parallel) poll with relaxed
// agent-scope atomic loads until != poison. One coherence round trip/step.
// ---------------------------------------------------------------------------
__global__ __launch_bounds__(256, 1) void lstm_kernel(
    const float* __restrict__ xg_f, const float* __restrict__ xg_b,
    const float* __restrict__ w_hh_f, const float* __restrict__ w_hh_b,
    const float* __restrict__ h0, const float* __restrict__ c0,
    float* __restrict__ hf, float* __restrict__ hb)
{
    const int bx    = blockIdx.x;
    const int dir   = bx >> 3;
    const int slice = bx & 7;
    const int t     = threadIdx.x;

    const float* xg   = dir ? xg_b  : xg_f;
    const float* w_hh = dir ? w_hh_b : w_hh_f;
    float* hout = dir ? hb : hf;

    __shared__ float h_lds[HHID];
    __shared__ float gbuf[128];

    const int lr   = t >> 1;          // 0..127 local gate row
    const int half = t & 1;           // which 128-elem half of k
    const int type = lr >> 5;         // 0..3 = i,f,g,o
    const int ul   = lr & 31;
    const int unit = slice * 32 + ul;
    const int grow = type * HHID + unit;   // global gate row in [0,1024)

    // Load weights into registers (one-time), then PIN them: the opaque asm
    // makes each value untouchable for rematerialization, so the 128 loads
    // cannot be sunk into the step loop. ~180-230 VGPR, fits (1 block/CU).
    float w[128];
    #pragma unroll
    for (int j = 0; j < 128; ++j)
        w[j] = w_hh[(size_t)grow * HHID + half * 128 + j];
    #pragma unroll
    for (int j = 0; j < 128; ++j)
        asm volatile("" : "+v"(w[j]));

    float c_reg = 0.f;
    if (t < 32) c_reg = c0[dir * HHID + slice * 32 + t];

    for (int n = 0; n < SEQ; ++n) {
        const int s = dir ? (SEQ - 1 - n) : n;

        // Prefetch xg for this step (independent of h, issues before poll)
        float xgi = 0.f, xgff = 0.f, xgg = 0.f, xgo = 0.f;
        if (t < 32) {
            const float* xb = xg + (size_t)s * G4 + slice * 32 + t;
            xgi  = xb[0];
            xgff = xb[256];
            xgg  = xb[512];
            xgo  = xb[768];
        }

        // Obtain h_prev into LDS
        if (n == 0) {
            h_lds[t] = h0[dir * HHID + t];
        } else if (t < 64) {
            const int sp = dir ? (s + 1) : (s - 1);
            unsigned int* src = (unsigned int*)(hout + (size_t)sp * HHID) + t * 4;
            unsigned got = 0;
            float hv[4];
            while (got != 0xFu) {
                #pragma unroll
                for (int j = 0; j < 4; ++j) {
                    if (!((got >> j) & 1u)) {
                        unsigned v = __hip_atomic_load(src + j, __ATOMIC_RELAXED,
                                                       __HIP_MEMORY_SCOPE_AGENT);
                        if (v != POISON) {
                            hv[j] = __uint_as_float(v);
                            got |= 1u << j;
                        }
                    }
                }
            }
            #pragma unroll
            for (int j = 0; j < 4; ++j) h_lds[t * 4 + j] = hv[j];
        }
        __syncthreads();

        // 128-element partial dot (weights in registers, h broadcast from LDS)
        float acc = 0.f;
        const float4* hv4 = (const float4*)(h_lds + half * 128);
        #pragma unroll
        for (int j4 = 0; j4 < 32; ++j4) {
            float4 hv = hv4[j4];
            acc += w[j4 * 4 + 0] * hv.x;
            acc += w[j4 * 4 + 1] * hv.y;
            acc += w[j4 * 4 + 2] * hv.z;
            acc += w[j4 * 4 + 3] * hv.w;
        }
        acc += __shfl_xor(acc, 1);       // combine the two halves
        if (half == 0) gbuf[lr] = acc;
        __syncthreads();

        // Gate activations + state update (32 unit-threads), then
        // device-coherent fire-and-forget store of h (data IS the flag).
        if (t < 32) {
            float gi = gbuf[t]      + xgi;
            float gf = gbuf[32 + t] + xgff;
            float gg = gbuf[64 + t] + xgg;
            float go = gbuf[96 + t] + xgo;
            float iv = 1.f / (1.f + __expf(-gi));
            float fv = 1.f / (1.f + __expf(-gf));
            float gv = 1.f - 2.f / (__expf(2.f * gg) + 1.f);   // tanh
            float ov = 1.f / (1.f + __expf(-go));
            float c  = fv * c_reg + iv * gv;
            c_reg = c;
            float h  = ov * (1.f - 2.f / (__expf(2.f * c) + 1.f));
            unsigned int* dst = (unsigned int*)(hout + (size_t)s * HHID) + slice * 32 + t;
            __hip_atomic_store(dst, __float_as_uint(h), __ATOMIC_RELAXED,
                               __HIP_MEMORY_SCOPE_AGENT);
        }
        // No trailing barrier: next iteration's h_lds writers (t<64) all
        // passed the gbuf barrier above, and gbuf/h_lds are disjoint.
    }
}

// ---------------------------------------------------------------------------
// Kernel 3: frames = [hf|hb] @ W_out^T + b_out      (4096 x 9)
// ---------------------------------------------------------------------------
__global__ __launch_bounds__(256) void frames_kernel(
    const float* __restrict__ hf, const float* __restrict__ hb,
    const float* __restrict__ W_out, const float* __restrict__ b_out,
    float* __restrict__ frames)
{
    int o = blockIdx.x * 256 + threadIdx.x;
    if (o >= SEQ * NT) return;
    int s = o / NT;
    int j = o - s * NT;
    const float4* a0 = (const float4*)(hf + (size_t)s * HHID);
    const float4* a1 = (const float4*)(hb + (size_t)s * HHID);
    const float4* w0 = (const float4*)(W_out + (size_t)j * 512);
    const float4* w1 = w0 + 64;
    float acc = 0.f;
    #pragma unroll 8
    for (int i = 0; i < 64; ++i) {
        float4 a = a0[i], b = w0[i];
        acc += a.x * b.x + a.y * b.y + a.z * b.z + a.w * b.w;
        float4 c = a1[i], d = w1[i];
        acc += c.x * d.x + c.y * d.y + c.z * d.z + c.w * d.w;
    }
    frames[o] = acc + b_out[j];
}

// ---------------------------------------------------------------------------
// Kernel 4: fused CRF forward + backtrack. ONE wave (64 threads), no inner-
// loop barriers. Per-lane alpha (lanes 0..8 meaningful), cross-lane reads via
// __shfl (always executed by ALL lanes — shfl from an inactive lane returns
// garbage/0, which was the R3 bug). Backpointers live in LDS only; t0
// backtracks at the end and writes tags directly to dout. Score -> dout[0].
// ---------------------------------------------------------------------------
__global__ __launch_bounds__(64) void crf_kernel(
    const float* __restrict__ frames, const float* __restrict__ trans,
    float* __restrict__ dout)
{
    __shared__ float fr[512 * NT];                 // 18432 B chunk of frames
    __shared__ unsigned char bpl[SEQ * NT];        // 36864 B backpointers
    const int t = threadIdx.x;
    const int tc = (t < NT) ? t : 0;               // clamped lane for fr reads

    float trow[NT];
    #pragma unroll
    for (int i = 0; i < NT; ++i) trow[i] = 0.f;
    if (t < NT) {
        #pragma unroll
        for (int i = 0; i < NT; ++i) trow[i] = trans[i * NT + t];
    }
    float alpha = (t == TSTART) ? 0.f : NEGV;      // lane t holds alpha[t]

    for (int chunk = 0; chunk < 8; ++chunk) {
        for (int idx = t; idx < 512 * NT; idx += 64)
            fr[idx] = frames[chunk * 512 * NT + idx];
        __syncthreads();   // single wave: cheap

        for (int sl = 0; sl < 512; ++sl) {
            const int s = chunk * 512 + sl;
            float v[NT];
            #pragma unroll
            for (int i = 0; i < NT; ++i)
                v[i] = __shfl(alpha, i) + trow[i];     // all lanes active
            float mx = v[0];
            int   am = 0;
            #pragma unroll
            for (int i = 1; i < NT; ++i)
                if (v[i] > mx) { mx = v[i]; am = i; }
            float sum = 0.f;
            #pragma unroll
            for (int i = 0; i < NT; ++i) sum += __expf(v[i] - mx);
            float anew = fr[sl * NT + tc] + mx + __logf(sum);
            if (t < NT) {
                bpl[s * NT + t] = (unsigned char)am;
                alpha = anew;
            }
        }
        __syncthreads();
    }

    // final: fin[j] = alpha[j] + trans[j, STOP]; gather with ALL lanes active
    float fin = NEGV;
    if (t < NT) fin = alpha + trans[t * NT + TSTOP];
    float f[NT];
    #pragma unroll
    for (int j = 0; j < NT; ++j) f[j] = __shfl(fin, j);  // all lanes active

    if (t == 0) {
        float mx = f[0];
        int best = 0;
        #pragma unroll
        for (int j = 1; j < NT; ++j)
            if (f[j] > mx) { mx = f[j]; best = j; }
        float sum = 0.f;
        #pragma unroll
        for (int j = 0; j < NT; ++j) sum += __expf(f[j] - mx);
        dout[0] = mx + __logf(sum);

        // backtrack entirely from LDS, stream tags straight to dout
        int cur = best;
        dout[1 + SEQ - 1] = (float)cur;
        for (int s = SEQ - 2; s >= 0; --s) {
            cur = bpl[(s + 1) * NT + cur];
            dout[1 + s] = (float)cur;
        }
    }
}

// ---------------------------------------------------------------------------
extern "C" void kernel_launch(void* const* d_in, const int* in_sizes, int n_in,
                              void* d_out, int out_size, void* d_ws, size_t ws_size,
                              hipStream_t stream)
{
    const int*   sentence = (const int*)  d_in[0];
    const float* embed    = (const float*)d_in[1];
    const float* w_ih_f   = (const float*)d_in[2];
    const float* w_hh_f   = (const float*)d_in[3];
    const float* b_ih_f   = (const float*)d_in[4];
    const float* b_hh_f   = (const float*)d_in[5];
    const float* w_ih_b   = (const float*)d_in[6];
    const float* w_hh_b   = (const float*)d_in[7];
    const float* b_ih_b   = (const float*)d_in[8];
    const float* b_hh_b   = (const float*)d_in[9];
    const float* h0       = (const float*)d_in[10];
    const float* c0       = (const float*)d_in[11];
    const float* W_out    = (const float*)d_in[12];
    const float* b_out    = (const float*)d_in[13];
    const float* trans    = (const float*)d_in[14];

    float* out = (float*)d_out;
    char*  ws  = (char*)d_ws;

    float* xg_f   = (float*)(ws + WS_XG_F);
    float* xg_b   = (float*)(ws + WS_XG_B);
    float* hf     = (float*)(ws + WS_HF);
    float* hb     = (float*)(ws + WS_HB);
    float* frames = (float*)(ws + WS_FRAMES);

    // Ensure hf/hb are poison (the "not yet written" sentinel) regardless of
    // harness state. hf and hb are contiguous: one 8 MB async memset.
    hipMemsetAsync(hf, 0xAA, 2u * SEQ * HHID * sizeof(float), stream);

    xgate_kernel<<<dim3(256, 2), 256, 0, stream>>>(
        sentence, embed, w_ih_f, b_ih_f, b_hh_f, w_ih_b, b_ih_b, b_hh_b,
        xg_f, xg_b);

    lstm_kernel<<<16, 256, 0, stream>>>(
        xg_f, xg_b, w_hh_f, w_hh_b, h0, c0, hf, hb);

    frames_kernel<<<(SEQ * NT + 255) / 256, 256, 0, stream>>>(
        hf, hb, W_out, b_out, frames);

    crf_kernel<<<1, 64, 0, stream>>>(frames, trans, out);
}

// Round 5
// 9920.036 us; speedup vs baseline: 1.0286x; 1.0286x over previous
//
#include <hip/hip_runtime.h>
#include <hip/hip_bf16.h>

// Problem constants
#define SEQ   4096
#define EMB   256
#define HHID  256      // HH
#define G4    1024     // 4*HH
#define NT    9        // tags
#define TSTART 7
#define TSTOP  8
#define NEGV  (-10000.0f)
#define POISON 0xAAAAAAAAu

// Workspace byte offsets (total ~42.2 MB)
#define WS_XG_F   0u            // 4096*1024 f32 = 16 MB
#define WS_XG_B   16777216u     // 16 MB
#define WS_HF     33554432u     // 4096*256 f32 = 4 MB
#define WS_HB     37748736u     // 4 MB
#define WS_FRAMES 41943040u     // 4096*9 f32 = 147456 B

// ---------------------------------------------------------------------------
// Kernel 1: x = embed[sentence]; xg = x @ w_ih^T + b_ih + b_hh  (both dirs)
// grid (256, 2), block 256. Each block: 16 sentence positions, all 1024 gates.
// ---------------------------------------------------------------------------
__global__ __launch_bounds__(256) void xgate_kernel(
    const int* __restrict__ sentence, const float* __restrict__ embed,
    const float* __restrict__ w_ih_f, const float* __restrict__ b_ih_f,
    const float* __restrict__ b_hh_f,
    const float* __restrict__ w_ih_b, const float* __restrict__ b_ih_b,
    const float* __restrict__ b_hh_b,
    float* __restrict__ xg_f, float* __restrict__ xg_b)
{
    const int st  = blockIdx.x;          // 0..255 (16 s each)
    const int dir = blockIdx.y;
    const float* w  = dir ? w_ih_b : w_ih_f;
    const float* bi = dir ? b_ih_b : b_ih_f;
    const float* bh = dir ? b_hh_b : b_hh_f;
    float* xg = dir ? xg_b : xg_f;
    const int t = threadIdx.x;

    __shared__ float x_t[EMB][16];       // transposed x tile
    for (int sl = 0; sl < 16; ++sl) {
        int s   = st * 16 + sl;
        int tok = sentence[s];
        x_t[t][sl] = embed[(size_t)tok * EMB + t];
    }
    __syncthreads();

    float acc[4][16];
    #pragma unroll
    for (int q = 0; q < 4; ++q)
        #pragma unroll
        for (int sl = 0; sl < 16; ++sl) acc[q][sl] = 0.f;

    #pragma unroll 4
    for (int e = 0; e < EMB; ++e) {
        float w0 = w[(size_t)(t        ) * EMB + e];
        float w1 = w[(size_t)(t + 256  ) * EMB + e];
        float w2 = w[(size_t)(t + 512  ) * EMB + e];
        float w3 = w[(size_t)(t + 768  ) * EMB + e];
        #pragma unroll
        for (int sl = 0; sl < 16; ++sl) {
            float xv = x_t[e][sl];
            acc[0][sl] += w0 * xv;
            acc[1][sl] += w1 * xv;
            acc[2][sl] += w2 * xv;
            acc[3][sl] += w3 * xv;
        }
    }

    #pragma unroll
    for (int q = 0; q < 4; ++q) {
        int g = t + 256 * q;
        float bb = bi[g] + bh[g];
        for (int sl = 0; sl < 16; ++sl) {
            xg[(size_t)(st * 16 + sl) * G4 + g] = acc[q][sl] + bb;
        }
    }
}

// ---------------------------------------------------------------------------
// Kernel 2: bidirectional LSTM recurrence. 16 blocks x 256 threads.
// blocks 0..7 = forward slices, 8..15 = backward slices.
//
// Thread t = (unit rb = t>>3 within slice, col-block cb = t&7).
// Each thread: partials of ALL 4 gates of unit (slice*32+rb) over 32 h-cols.
// Weights (128 fp32/thread) held in AGPRs via explicit v_accvgpr_write/read
// (guaranteed residency — the VGPR allocator refused to keep them, R2-R4).
// 8-lane shfl_xor reduce -> lane cb==0 owns all 4 gates of its unit, does
// activations + c-state + h store. ONE __syncthreads per step.
//
// h exchange: data-carrying poison poll (hf/hb pre-poisoned 0xAAAAAAAA).
// Producers: relaxed agent-scope atomic store (fire-and-forget; data=flag).
// Consumers: 1 word/thread relaxed agent-scope poll for the 224 non-local
// words; own 32 words short-circuit through LDS ping-pong buf[2][256].
// ---------------------------------------------------------------------------
__global__ __launch_bounds__(256, 1) void lstm_kernel(
    const float* __restrict__ xg_f, const float* __restrict__ xg_b,
    const float* __restrict__ w_hh_f, const float* __restrict__ w_hh_b,
    const float* __restrict__ h0, const float* __restrict__ c0,
    float* __restrict__ hf, float* __restrict__ hb)
{
    const int bx    = blockIdx.x;
    const int dir   = bx >> 3;
    const int slice = bx & 7;
    const int t     = threadIdx.x;
    const int cb    = t & 7;          // col block: h cols cb*32 .. cb*32+31
    const int rb    = t >> 3;         // unit within slice (0..31)
    const int unit  = slice * 32 + rb;

    const float* xg   = dir ? xg_b  : xg_f;
    const float* w_hh = dir ? w_hh_b : w_hh_f;
    float* hout = dir ? hb : hf;

    __shared__ float buf[2][HHID];    // h ping-pong

    // --- weights into AGPRs: wa[q*32+j] = W[q*256+unit][cb*32+j] ---
    float wa[128];
    #pragma unroll
    for (int q = 0; q < 4; ++q) {
        #pragma unroll
        for (int j = 0; j < 32; ++j) {
            float tmp = w_hh[(size_t)(q * HHID + unit) * HHID + cb * 32 + j];
            asm volatile("v_accvgpr_write_b32 %0, %1"
                         : "=a"(wa[q * 32 + j]) : "v"(tmp));
        }
    }

    float c_reg = 0.f;
    if (cb == 0) c_reg = c0[dir * HHID + unit];

    const bool own = (t >= slice * 32) && (t < slice * 32 + 32);

    for (int n = 0; n < SEQ; ++n) {
        const int s = dir ? (SEQ - 1 - n) : n;

        // Prefetch xg (independent of h; issues before the poll)
        float xg0 = 0.f, xg1 = 0.f, xg2 = 0.f, xg3 = 0.f;
        if (cb == 0) {
            const float* xb = xg + (size_t)s * G4 + unit;
            xg0 = xb[0];
            xg1 = xb[HHID];
            xg2 = xb[2 * HHID];
            xg3 = xb[3 * HHID];
        }

        // Obtain h_prev word t into LDS (own 32 words arrive via local path)
        if (n == 0) {
            buf[0][t] = h0[dir * HHID + t];
        } else if (!own) {
            const int sp = dir ? (s + 1) : (s - 1);
            const unsigned int* src =
                (const unsigned int*)(hout + (size_t)sp * HHID) + t;
            unsigned v;
            do {
                v = __hip_atomic_load(src, __ATOMIC_RELAXED,
                                      __HIP_MEMORY_SCOPE_AGENT);
            } while (v == POISON);
            buf[n & 1][t] = __uint_as_float(v);
        }
        __syncthreads();

        // 32-col partial dot for 4 gates (weights from AGPRs, h from LDS)
        float a0 = 0.f, a1 = 0.f, a2 = 0.f, a3 = 0.f;
        const float4* h4 = (const float4*)(&buf[n & 1][cb * 32]);
        #pragma unroll
        for (int j4 = 0; j4 < 8; ++j4) {
            float4 hv = h4[j4];
            #pragma unroll
            for (int k = 0; k < 4; ++k) {
                float hk = (k == 0) ? hv.x : (k == 1) ? hv.y
                         : (k == 2) ? hv.z : hv.w;
                float w0, w1, w2, w3;
                asm volatile("v_accvgpr_read_b32 %0, %1"
                             : "=v"(w0) : "a"(wa[0 * 32 + j4 * 4 + k]));
                asm volatile("v_accvgpr_read_b32 %0, %1"
                             : "=v"(w1) : "a"(wa[1 * 32 + j4 * 4 + k]));
                asm volatile("v_accvgpr_read_b32 %0, %1"
                             : "=v"(w2) : "a"(wa[2 * 32 + j4 * 4 + k]));
                asm volatile("v_accvgpr_read_b32 %0, %1"
                             : "=v"(w3) : "a"(wa[3 * 32 + j4 * 4 + k]));
                a0 += w0 * hk;
                a1 += w1 * hk;
                a2 += w2 * hk;
                a3 += w3 * hk;
            }
        }

        // 8-lane butterfly reduce across col blocks (lanes cb = t&7)
        #pragma unroll
        for (int m = 1; m <= 4; m <<= 1) {
            a0 += __shfl_xor(a0, m);
            a1 += __shfl_xor(a1, m);
            a2 += __shfl_xor(a2, m);
            a3 += __shfl_xor(a3, m);
        }

        // Lane cb==0: activations, state, h store (global + local shortcut)
        if (cb == 0) {
            float gi = a0 + xg0;
            float gf = a1 + xg1;
            float gg = a2 + xg2;
            float go = a3 + xg3;
            float iv = 1.f / (1.f + __expf(-gi));
            float fv = 1.f / (1.f + __expf(-gf));
            float gv = 1.f - 2.f / (__expf(2.f * gg) + 1.f);   // tanh
            float ov = 1.f / (1.f + __expf(-go));
            float c  = fv * c_reg + iv * gv;
            c_reg = c;
            float h  = ov * (1.f - 2.f / (__expf(2.f * c) + 1.f));
            unsigned int* dst =
                (unsigned int*)(hout + (size_t)s * HHID) + unit;
            __hip_atomic_store(dst, __float_as_uint(h), __ATOMIC_RELAXED,
                               __HIP_MEMORY_SCOPE_AGENT);
            buf[(n + 1) & 1][unit] = h;   // local shortcut for next step
        }
        // No second barrier: writes above target buf[(n+1)&1]; concurrent
        // readers of this step use buf[n&1]. The next iteration's single
        // barrier orders buf[(n+1)&1] for its dot.
    }
}

// ---------------------------------------------------------------------------
// Kernel 3: frames = [hf|hb] @ W_out^T + b_out      (4096 x 9)
// ---------------------------------------------------------------------------
__global__ __launch_bounds__(256) void frames_kernel(
    const float* __restrict__ hf, const float* __restrict__ hb,
    const float* __restrict__ W_out, const float* __restrict__ b_out,
    float* __restrict__ frames)
{
    int o = blockIdx.x * 256 + threadIdx.x;
    if (o >= SEQ * NT) return;
    int s = o / NT;
    int j = o - s * NT;
    const float4* a0 = (const float4*)(hf + (size_t)s * HHID);
    const float4* a1 = (const float4*)(hb + (size_t)s * HHID);
    const float4* w0 = (const float4*)(W_out + (size_t)j * 512);
    const float4* w1 = w0 + 64;
    float acc = 0.f;
    #pragma unroll 8
    for (int i = 0; i < 64; ++i) {
        float4 a = a0[i], b = w0[i];
        acc += a.x * b.x + a.y * b.y + a.z * b.z + a.w * b.w;
        float4 c = a1[i], d = w1[i];
        acc += c.x * d.x + c.y * d.y + c.z * d.z + c.w * d.w;
    }
    frames[o] = acc + b_out[j];
}

// ---------------------------------------------------------------------------
// Kernel 4: fused CRF forward + backtrack. ONE wave (64 threads), no inner-
// loop barriers. Per-lane alpha (lanes 0..8 meaningful), cross-lane reads via
// __shfl executed by ALL lanes. Backpointers in LDS; t0 backtracks at the
// end and writes tags directly to dout. Score -> dout[0].
// ---------------------------------------------------------------------------
__global__ __launch_bounds__(64) void crf_kernel(
    const float* __restrict__ frames, const float* __restrict__ trans,
    float* __restrict__ dout)
{
    __shared__ float fr[512 * NT];                 // 18432 B chunk of frames
    __shared__ unsigned char bpl[SEQ * NT];        // 36864 B backpointers
    const int t = threadIdx.x;
    const int tc = (t < NT) ? t : 0;               // clamped lane for fr reads

    float trow[NT];
    #pragma unroll
    for (int i = 0; i < NT; ++i) trow[i] = 0.f;
    if (t < NT) {
        #pragma unroll
        for (int i = 0; i < NT; ++i) trow[i] = trans[i * NT + t];
    }
    float alpha = (t == TSTART) ? 0.f : NEGV;      // lane t holds alpha[t]

    for (int chunk = 0; chunk < 8; ++chunk) {
        for (int idx = t; idx < 512 * NT; idx += 64)
            fr[idx] = frames[chunk * 512 * NT + idx];
        __syncthreads();   // single wave: cheap

        for (int sl = 0; sl < 512; ++sl) {
            const int s = chunk * 512 + sl;
            float v[NT];
            #pragma unroll
            for (int i = 0; i < NT; ++i)
                v[i] = __shfl(alpha, i) + trow[i];     // all lanes active
            float mx = v[0];
            int   am = 0;
            #pragma unroll
            for (int i = 1; i < NT; ++i)
                if (v[i] > mx) { mx = v[i]; am = i; }
            float sum = 0.f;
            #pragma unroll
            for (int i = 0; i < NT; ++i) sum += __expf(v[i] - mx);
            float anew = fr[sl * NT + tc] + mx + __logf(sum);
            if (t < NT) {
                bpl[s * NT + t] = (unsigned char)am;
                alpha = anew;
            }
        }
        __syncthreads();
    }

    // final: fin[j] = alpha[j] + trans[j, STOP]; gather with ALL lanes active
    float fin = NEGV;
    if (t < NT) fin = alpha + trans[t * NT + TSTOP];
    float f[NT];
    #pragma unroll
    for (int j = 0; j < NT; ++j) f[j] = __shfl(fin, j);  // all lanes active

    if (t == 0) {
        float mx = f[0];
        int best = 0;
        #pragma unroll
        for (int j = 1; j < NT; ++j)
            if (f[j] > mx) { mx = f[j]; best = j; }
        float sum = 0.f;
        #pragma unroll
        for (int j = 0; j < NT; ++j) sum += __expf(f[j] - mx);
        dout[0] = mx + __logf(sum);

        // backtrack entirely from LDS, stream tags straight to dout
        int cur = best;
        dout[1 + SEQ - 1] = (float)cur;
        for (int s = SEQ - 2; s >= 0; --s) {
            cur = bpl[(s + 1) * NT + cur];
            dout[1 + s] = (float)cur;
        }
    }
}

// ---------------------------------------------------------------------------
extern "C" void kernel_launch(void* const* d_in, const int* in_sizes, int n_in,
                              void* d_out, int out_size, void* d_ws, size_t ws_size,
                              hipStream_t stream)
{
    const int*   sentence = (const int*)  d_in[0];
    const float* embed    = (const float*)d_in[1];
    const float* w_ih_f   = (const float*)d_in[2];
    const float* w_hh_f   = (const float*)d_in[3];
    const float* b_ih_f   = (const float*)d_in[4];
    const float* b_hh_f   = (const float*)d_in[5];
    const float* w_ih_b   = (const float*)d_in[6];
    const float* w_hh_b   = (const float*)d_in[7];
    const float* b_ih_b   = (const float*)d_in[8];
    const float* b_hh_b   = (const float*)d_in[9];
    const float* h0       = (const float*)d_in[10];
    const float* c0       = (const float*)d_in[11];
    const float* W_out    = (const float*)d_in[12];
    const float* b_out    = (const float*)d_in[13];
    const float* trans    = (const float*)d_in[14];

    float* out = (float*)d_out;
    char*  ws  = (char*)d_ws;

    float* xg_f   = (float*)(ws + WS_XG_F);
    float* xg_b   = (float*)(ws + WS_XG_B);
    float* hf     = (float*)(ws + WS_HF);
    float* hb     = (float*)(ws + WS_HB);
    float* frames = (float*)(ws + WS_FRAMES);

    // Ensure hf/hb are poison (the "not yet written" sentinel) regardless of
    // harness state. hf and hb are contiguous: one 8 MB async memset.
    hipMemsetAsync(hf, 0xAA, 2u * SEQ * HHID * sizeof(float), stream);

    xgate_kernel<<<dim3(256, 2), 256, 0, stream>>>(
        sentence, embed, w_ih_f, b_ih_f, b_hh_f, w_ih_b, b_ih_b, b_hh_b,
        xg_f, xg_b);

    lstm_kernel<<<16, 256, 0, stream>>>(
        xg_f, xg_b, w_hh_f, w_hh_b, h0, c0, hf, hb);

    frames_kernel<<<(SEQ * NT + 255) / 256, 256, 0, stream>>>(
        hf, hb, W_out, b_out, frames);

    crf_kernel<<<1, 64, 0, stream>>>(frames, trans, out);
}